// Round 1
// baseline (2905.023 us; speedup 1.0000x reference)
//
#include <hip/hip_runtime.h>
#include <math.h>

typedef unsigned short u16;
typedef unsigned int u32;
typedef unsigned long long u64;
typedef __attribute__((ext_vector_type(8))) short short8;
typedef __attribute__((ext_vector_type(4))) float f32x4;

#define B_IMG 16
#define H2 28
#define EMB 1536
#define NPATCH 784
#define Q_TOT (B_IMG * NPATCH)   // 12544
#define NCORE 16384
#define IMG 224
#define KS 33
#define HALF 16

// ---------- helpers ----------

__device__ __forceinline__ u16 f2bf(float f) {
    u32 u = __float_as_uint(f);
    u32 r = u + 0x7FFFu + ((u >> 16) & 1u);   // RNE
    return (u16)(r >> 16);
}
__device__ __forceinline__ float bf2f(u16 h) {
    return __uint_as_float(((u32)h) << 16);
}
// monotonic total-order mapping for f32 (handles negatives from rounding)
__device__ __forceinline__ u32 fkey(float f) {
    u32 u = __float_as_uint(f);
    return (u & 0x80000000u) ? ~u : (u | 0x80000000u);
}
__device__ __forceinline__ float fkey_inv(u32 k) {
    u32 u = (k & 0x80000000u) ? (k ^ 0x80000000u) : ~k;
    return __uint_as_float(u);
}

// async global->LDS, 16B per lane (CK reinterpret-through-uintptr pattern)
__device__ __forceinline__ void async_copy16(const u16* gsrc, u16* ldst) {
    auto g = reinterpret_cast<const __attribute__((address_space(1))) u32*>(
        reinterpret_cast<uintptr_t>(gsrc));
    auto l = reinterpret_cast<__attribute__((address_space(3))) u32*>(
        reinterpret_cast<uintptr_t>(ldst));
    __builtin_amdgcn_global_load_lds(g, l, 16, 0, 0);
}

// ---------- 0: init scratch ----------
__global__ void k_init(float* a2, u64* minkey) {
    int i = blockIdx.x * 256 + threadIdx.x;
    if (i < Q_TOT) { a2[i] = 0.f; minkey[i] = ~0ull; }
}

// ---------- 1: split coreset into bf16 hi/lo + row norms ----------
__global__ void k_split_cs(const float* __restrict__ cs, u16* __restrict__ cshi,
                           u16* __restrict__ cslo, float* __restrict__ b2) {
    __shared__ float sm[4];
    const int n = blockIdx.x;
    const int t = threadIdx.x;
    const size_t base = (size_t)n * EMB;
    float s = 0.f;
#pragma unroll
    for (int i = 0; i < 6; ++i) {
        const int e = t + i * 256;
        float v = cs[base + e];
        u16 hb = f2bf(v);
        u16 lb = f2bf(v - bf2f(hb));
        cshi[base + e] = hb;
        cslo[base + e] = lb;
        s += v * v;
    }
#pragma unroll
    for (int off = 32; off > 0; off >>= 1) s += __shfl_down(s, off, 64);
    if ((t & 63) == 0) sm[t >> 6] = s;
    __syncthreads();
    if (t == 0) b2[n] = sm[0] + sm[1] + sm[2] + sm[3];
}

// ---------- 2: avgpool(3,1,1) both layers + 2x nearest upsample of layer3,
//              transpose to [q][e], split to bf16 hi/lo, accumulate a2 ----------
__global__ void k_build_x(const float* __restrict__ f2, const float* __restrict__ f3,
                          u16* __restrict__ xhi, u16* __restrict__ xlo,
                          float* __restrict__ a2) {
    __shared__ float tile[32][33];
    __shared__ float red[8][33];
    const int tx = threadIdx.x, ty = threadIdx.y;
    const int hw0 = blockIdx.x * 32;
    const int e0 = blockIdx.y * 32;
    const int b = blockIdx.z;
    const int hw = hw0 + tx;
    const bool ok = hw < NPATCH;
    const int h = hw / 28, w = hw - h * 28;
    float sq = 0.f;
#pragma unroll
    for (int j = 0; j < 4; ++j) {
        const int el = ty + 8 * j;
        const int e = e0 + el;
        float v = 0.f;
        if (ok) {
            if (e < 512) {
                const float* p = f2 + (size_t)(b * 512 + e) * 784;
#pragma unroll
                for (int dy = -1; dy <= 1; ++dy) {
                    int yy = h + dy;
                    if (yy < 0 || yy >= 28) continue;
#pragma unroll
                    for (int dx = -1; dx <= 1; ++dx) {
                        int xx = w + dx;
                        if (xx < 0 || xx >= 28) continue;
                        v += p[yy * 28 + xx];
                    }
                }
            } else {
                const int c = e - 512;
                const int y3 = h >> 1, x3 = w >> 1;
                const float* p = f3 + (size_t)(b * 1024 + c) * 196;
#pragma unroll
                for (int dy = -1; dy <= 1; ++dy) {
                    int yy = y3 + dy;
                    if (yy < 0 || yy >= 14) continue;
#pragma unroll
                    for (int dx = -1; dx <= 1; ++dx) {
                        int xx = x3 + dx;
                        if (xx < 0 || xx >= 14) continue;
                        v += p[yy * 14 + xx];
                    }
                }
            }
            v *= (1.0f / 9.0f);
        }
        tile[el][tx] = v;
        sq += v * v;
    }
    red[ty][tx] = sq;
    __syncthreads();
#pragma unroll
    for (int j = 0; j < 4; ++j) {
        const int hwl = ty + 8 * j;
        const int hw2 = hw0 + hwl;
        if (hw2 < NPATCH) {
            const int q = b * NPATCH + hw2;
            const float v = tile[tx][hwl];
            u16 hb = f2bf(v);
            u16 lb = f2bf(v - bf2f(hb));
            xhi[(size_t)q * EMB + e0 + tx] = hb;
            xlo[(size_t)q * EMB + e0 + tx] = lb;
        }
    }
    if (ty == 0 && ok) {
        float s = 0.f;
#pragma unroll
        for (int y = 0; y < 8; ++y) s += red[y][tx];
        atomicAdd(&a2[b * NPATCH + hw], s);
    }
}

// ---------- 3: split-bf16 distance GEMM with fused min/argmin ----------
// 128x128 tile, BK=32, 4 waves in 2x2, each wave 64x64 via 4x4 16x16x32 MFMAs.
// dot = ahi*bhi + ahi*blo + alo*bhi  (lo*lo term ~2^-18/el, negligible)
__global__ __launch_bounds__(256) void k_gemm(
    const u16* __restrict__ xhi, const u16* __restrict__ xlo,
    const u16* __restrict__ cshi, const u16* __restrict__ cslo,
    const float* __restrict__ a2, const float* __restrict__ b2,
    u64* __restrict__ minkey) {
    __shared__ short sA[2][128 * 32];
    __shared__ short sB[2][128 * 32];
    const int tid = threadIdx.x;
    const int lane = tid & 63;
    const int wid = tid >> 6;
    const int wy = wid >> 1;
    const int wx = wid & 1;
    const int qd = lane >> 4;
    const int lr = lane & 15;

    const int m0 = blockIdx.y * 128;
    const int n0 = blockIdx.x * 128;

    // staging map: chunk ch in [0,512), row=ch>>2, 16B col chunk = ch&3
    const int ch0 = tid, ch1 = tid + 256;
    const int rA0 = ch0 >> 2, c0 = (ch0 & 3) * 8;
    const int rA1 = ch1 >> 2, c1 = (ch1 & 3) * 8;
    const size_t gA0 = (size_t)(m0 + rA0) * EMB + c0;
    const size_t gA1 = (size_t)(m0 + rA1) * EMB + c1;
    const size_t gB0 = (size_t)(n0 + rA0) * EMB + c0;
    const size_t gB1 = (size_t)(n0 + rA1) * EMB + c1;

    f32x4 acc[4][4];
#pragma unroll
    for (int i = 0; i < 4; ++i)
#pragma unroll
        for (int j = 0; j < 4; ++j) acc[i][j] = (f32x4){0.f, 0.f, 0.f, 0.f};

    const int aoff = (wy * 64 + lr) * 32 + qd * 8;
    const int boff = (wx * 64 + lr) * 32 + qd * 8;

    for (int ks = 0; ks < 48; ++ks) {
        const int kk = ks * 32;
        __syncthreads();
        async_copy16(xhi + gA0 + kk, (u16*)&sA[0][ch0 * 8]);
        async_copy16(xhi + gA1 + kk, (u16*)&sA[0][ch1 * 8]);
        async_copy16(xlo + gA0 + kk, (u16*)&sA[1][ch0 * 8]);
        async_copy16(xlo + gA1 + kk, (u16*)&sA[1][ch1 * 8]);
        async_copy16(cshi + gB0 + kk, (u16*)&sB[0][ch0 * 8]);
        async_copy16(cshi + gB1 + kk, (u16*)&sB[0][ch1 * 8]);
        async_copy16(cslo + gB0 + kk, (u16*)&sB[1][ch0 * 8]);
        async_copy16(cslo + gB1 + kk, (u16*)&sB[1][ch1 * 8]);
        __syncthreads();

        short8 ah[4], al[4];
#pragma unroll
        for (int mi = 0; mi < 4; ++mi) {
            ah[mi] = *(const short8*)&sA[0][aoff + mi * 512];
            al[mi] = *(const short8*)&sA[1][aoff + mi * 512];
        }
#pragma unroll
        for (int nj = 0; nj < 4; ++nj) {
            short8 bh = *(const short8*)&sB[0][boff + nj * 512];
            short8 bl = *(const short8*)&sB[1][boff + nj * 512];
#pragma unroll
            for (int mi = 0; mi < 4; ++mi) {
                acc[mi][nj] = __builtin_amdgcn_mfma_f32_16x16x32_bf16(ah[mi], bh, acc[mi][nj], 0, 0, 0);
                acc[mi][nj] = __builtin_amdgcn_mfma_f32_16x16x32_bf16(ah[mi], bl, acc[mi][nj], 0, 0, 0);
                acc[mi][nj] = __builtin_amdgcn_mfma_f32_16x16x32_bf16(al[mi], bh, acc[mi][nj], 0, 0, 0);
            }
        }
    }

    // epilogue: d2 = a2[m] + b2[n] - 2*dot ; per-row min across this block's cols
    // C/D layout: col = lane&15 (n), row = quad*4 + reg (m)  [m89-verified]
#pragma unroll
    for (int mi = 0; mi < 4; ++mi) {
#pragma unroll
        for (int r = 0; r < 4; ++r) {
            const int m_l = wy * 64 + mi * 16 + qd * 4 + r;
            const float a2v = a2[m0 + m_l];
            u64 best = ~0ull;
#pragma unroll
            for (int nj = 0; nj < 4; ++nj) {
                const int n_l = wx * 64 + nj * 16 + lr;
                float d2 = a2v + b2[n0 + n_l] - 2.0f * acc[mi][nj][r];
                u64 key = ((u64)fkey(d2) << 32) | (u32)(n0 + n_l);
                best = best < key ? best : key;
            }
#pragma unroll
            for (int s = 1; s < 16; s <<= 1) {
                u64 o = __shfl_xor(best, s, 64);
                best = best < o ? best : o;
            }
            if (lr == 0) atomicMin(&minkey[m0 + m_l], best);
        }
    }
}

// ---------- 4: unpack min keys ----------
__global__ void k_finalize(const u64* __restrict__ minkey, float* __restrict__ scores,
                           int* __restrict__ locs) {
    int i = blockIdx.x * 256 + threadIdx.x;
    if (i < Q_TOT) {
        u64 k = minkey[i];
        float d2 = fkey_inv((u32)(k >> 32));
        scores[i] = sqrtf(fmaxf(d2, 1e-12f));
        locs[i] = (int)(k & 0xffffffffu);
    }
}

// ---------- 5: per-image argmax patch ----------
__global__ void k_argmax(const float* __restrict__ scores, const int* __restrict__ locs,
                         float* __restrict__ imgscore, int* __restrict__ nnidx,
                         int* __restrict__ qstar) {
    __shared__ u64 red[256];
    const int b = blockIdx.x, t = threadIdx.x;
    u64 best = 0;
    for (int p = t; p < NPATCH; p += 256) {
        u32 u = __float_as_uint(scores[b * NPATCH + p]);   // scores > 0
        u64 key = ((u64)u << 32) | (u32)(0xFFFFFFFFu - (u32)p);  // tie -> smallest p
        best = best > key ? best : key;
    }
    red[t] = best;
    __syncthreads();
    for (int s = 128; s > 0; s >>= 1) {
        if (t < s) { u64 o = red[t + s]; if (o > red[t]) red[t] = o; }
        __syncthreads();
    }
    if (t == 0) {
        u64 k = red[0];
        int p = (int)(0xFFFFFFFFu - (u32)(k & 0xFFFFFFFFu));
        imgscore[b] = __uint_as_float((u32)(k >> 32));
        nnidx[b] = locs[b * NPATCH + p];
        qstar[b] = b * NPATCH + p;
    }
}

// ---------- 6: d2 from each image's nn_sample to the whole coreset (fp32) ----------
__global__ void k_d2nn(const float* __restrict__ cs, const float* __restrict__ b2,
                       const int* __restrict__ nnidx, float* __restrict__ d2nn) {
    __shared__ float snn[16 * 512];
    const int t = threadIdx.x;
    const int n = blockIdx.x * 256 + t;
    float acc[16];
#pragma unroll
    for (int b = 0; b < 16; ++b) acc[b] = 0.f;
    for (int kc = 0; kc < EMB; kc += 512) {
        __syncthreads();
#pragma unroll
        for (int j = 0; j < 8; ++j) {
            int fid = t + j * 256;       // 0..2047 float4s
            int row = fid >> 7;
            int c4 = fid & 127;
            ((float4*)snn)[row * 128 + c4] =
                ((const float4*)(cs + (size_t)nnidx[row] * EMB + kc))[c4];
        }
        __syncthreads();
        const float4* csrow = (const float4*)(cs + (size_t)n * EMB + kc);
        for (int k4 = 0; k4 < 128; ++k4) {
            float4 c4 = csrow[k4];
#pragma unroll
            for (int b = 0; b < 16; ++b) {
                float4 nb = ((const float4*)snn)[b * 128 + k4];
                acc[b] += c4.x * nb.x + c4.y * nb.y + c4.z * nb.z + c4.w * nb.w;
            }
        }
    }
#pragma unroll
    for (int b = 0; b < 16; ++b)
        d2nn[b * NCORE + n] = b2[nnidx[b]] + b2[n] - 2.f * acc[b];
}

// ---------- 7: top-9 supports, d_sup, softmax weight, anomaly score ----------
__global__ void k_topk(const float* __restrict__ d2nn, const float* __restrict__ cs,
                       const u16* __restrict__ xhi, const u16* __restrict__ xlo,
                       const int* __restrict__ qstar, const float* __restrict__ imgscore,
                       float* __restrict__ out_scores) {
    __shared__ int sel_idx[9];
    __shared__ float dsup[9];
    __shared__ u64 red[256];
    __shared__ float fred[256];
    const int b = blockIdx.x, t = threadIdx.x;

    // 9 rounds of masked min (ascending, tie -> smaller index; matches top_k(-d))
    for (int j = 0; j < 9; ++j) {
        u64 best = ~0ull;
        for (int n = t; n < NCORE; n += 256) {
            bool skip = false;
            for (int jj = 0; jj < j; ++jj) skip |= (sel_idx[jj] == n);
            if (skip) continue;
            u64 key = ((u64)fkey(d2nn[b * NCORE + n]) << 32) | (u32)n;
            best = best < key ? best : key;
        }
        red[t] = best;
        __syncthreads();
        for (int s = 128; s > 0; s >>= 1) {
            if (t < s) { u64 o = red[t + s]; if (o < red[t]) red[t] = o; }
            __syncthreads();
        }
        if (t == 0) sel_idx[j] = (int)(red[0] & 0xffffffffu);
        __syncthreads();
    }

    // d_sup[j] = ||mpf - coreset[sel_idx[j]]||  (diff-square-sum like the reference)
    const int q = qstar[b];
    for (int j = 0; j < 9; ++j) {
        const int s = sel_idx[j];
        float p = 0.f;
        for (int e = t; e < EMB; e += 256) {
            float mv = bf2f(xhi[(size_t)q * EMB + e]) + bf2f(xlo[(size_t)q * EMB + e]);
            float d = mv - cs[(size_t)s * EMB + e];
            p += d * d;
        }
        fred[t] = p;
        __syncthreads();
        for (int ss = 128; ss > 0; ss >>= 1) {
            if (t < ss) fred[t] += fred[t + ss];
            __syncthreads();
        }
        if (t == 0) dsup[j] = sqrtf(fmaxf(fred[0], 1e-12f));
        __syncthreads();
    }

    if (t == 0) {
        float m = dsup[0];
        for (int j = 1; j < 9; ++j) m = fmaxf(m, dsup[j]);
        float se = 0.f, e0 = 0.f;
        for (int j = 0; j < 9; ++j) {
            float e = expf(dsup[j] - m);
            se += e;
            if (j == 0) e0 = e;
        }
        out_scores[b] = (1.0f - e0 / se) * imgscore[b];
    }
}

// ---------- 8: bilinear 28->224 (jax.image.resize half-pixel + edge clamp) ----------
__global__ void k_bilinear(const float* __restrict__ scores, float* __restrict__ map0) {
    int i = blockIdx.x * 256 + threadIdx.x;
    if (i >= B_IMG * IMG * IMG) return;
    int b = i / (IMG * IMG);
    int rem = i - b * (IMG * IMG);
    int y = rem / IMG, x = rem - y * IMG;
    float cy = (y + 0.5f) * 0.125f - 0.5f;
    float cx = (x + 0.5f) * 0.125f - 0.5f;
    float fy = cy - floorf(cy), fx = cx - floorf(cx);
    int y0 = (int)floorf(cy), x0 = (int)floorf(cx);
    int y1 = min(max(y0 + 1, 0), 27), x1 = min(max(x0 + 1, 0), 27);
    y0 = min(max(y0, 0), 27);
    x0 = min(max(x0, 0), 27);
    const float* s = scores + b * NPATCH;
    map0[i] = (1.f - fy) * ((1.f - fx) * s[y0 * 28 + x0] + fx * s[y0 * 28 + x1]) +
              fy * ((1.f - fx) * s[y1 * 28 + x0] + fx * s[y1 * 28 + x1]);
}

// ---------- 9/10: separable 33-tap Gaussian, sigma=4, reflect padding ----------
__global__ void k_blur_v(const float* __restrict__ src, float* __restrict__ dst) {
    __shared__ float wk[KS];
    int t = threadIdx.x;
    if (t < KS) { float d = (float)(t - HALF); wk[t] = expf(-(d * d) / 32.0f); }
    __syncthreads();
    float wsum = 0.f;
#pragma unroll
    for (int j = 0; j < KS; ++j) wsum += wk[j];
    int i = blockIdx.x * 256 + t;
    if (i >= B_IMG * IMG * IMG) return;
    int b = i / (IMG * IMG);
    int rem = i - b * (IMG * IMG);
    int y = rem / IMG, x = rem - y * IMG;
    float acc = 0.f;
#pragma unroll
    for (int j = 0; j < KS; ++j) {
        int yy = y - HALF + j;
        yy = yy < 0 ? -yy : (yy > 223 ? 446 - yy : yy);
        acc += wk[j] * src[b * (IMG * IMG) + yy * IMG + x];
    }
    dst[i] = acc / wsum;
}

__global__ void k_blur_h(const float* __restrict__ src, float* __restrict__ dst) {
    __shared__ float wk[KS];
    int t = threadIdx.x;
    if (t < KS) { float d = (float)(t - HALF); wk[t] = expf(-(d * d) / 32.0f); }
    __syncthreads();
    float wsum = 0.f;
#pragma unroll
    for (int j = 0; j < KS; ++j) wsum += wk[j];
    int i = blockIdx.x * 256 + t;
    if (i >= B_IMG * IMG * IMG) return;
    int b = i / (IMG * IMG);
    int rem = i - b * (IMG * IMG);
    int y = rem / IMG, x = rem - y * IMG;
    float acc = 0.f;
#pragma unroll
    for (int j = 0; j < KS; ++j) {
        int xx = x - HALF + j;
        xx = xx < 0 ? -xx : (xx > 223 ? 446 - xx : xx);
        acc += wk[j] * src[b * (IMG * IMG) + y * IMG + xx];
    }
    dst[i] = acc / wsum;
}

// ---------- launch ----------
extern "C" void kernel_launch(void* const* d_in, const int* in_sizes, int n_in,
                              void* d_out, int out_size, void* d_ws, size_t ws_size,
                              hipStream_t stream) {
    const float* f2 = (const float*)d_in[0];
    const float* f3 = (const float*)d_in[1];
    const float* cs = (const float*)d_in[2];
    float* out = (float*)d_out;

    char* w = (char*)d_ws;
    auto alloc = [&](size_t bytes) {
        char* p = w;
        w += (bytes + 255) & ~(size_t)255;
        return p;
    };
    u16* xhi = (u16*)alloc((size_t)Q_TOT * EMB * 2);
    u16* xlo = (u16*)alloc((size_t)Q_TOT * EMB * 2);
    u16* cshi = (u16*)alloc((size_t)NCORE * EMB * 2);
    u16* cslo = (u16*)alloc((size_t)NCORE * EMB * 2);
    float* a2 = (float*)alloc(Q_TOT * 4);
    float* b2 = (float*)alloc(NCORE * 4);
    u64* minkey = (u64*)alloc(Q_TOT * 8);
    float* scores = (float*)alloc(Q_TOT * 4);
    int* locs = (int*)alloc(Q_TOT * 4);
    float* imgscore = (float*)alloc(B_IMG * 4);
    int* nnidx = (int*)alloc(B_IMG * 4);
    int* qstar = (int*)alloc(B_IMG * 4);
    float* d2nn = (float*)alloc((size_t)B_IMG * NCORE * 4);
    float* map0 = (float*)alloc((size_t)B_IMG * IMG * IMG * 4);
    float* map1 = (float*)alloc((size_t)B_IMG * IMG * IMG * 4);

    k_init<<<49, 256, 0, stream>>>(a2, minkey);
    k_split_cs<<<NCORE, 256, 0, stream>>>(cs, cshi, cslo, b2);
    k_build_x<<<dim3(25, 48, 16), dim3(32, 8), 0, stream>>>(f2, f3, xhi, xlo, a2);
    k_gemm<<<dim3(128, 98), 256, 0, stream>>>(xhi, xlo, cshi, cslo, a2, b2, minkey);
    k_finalize<<<49, 256, 0, stream>>>(minkey, scores, locs);
    k_argmax<<<16, 256, 0, stream>>>(scores, locs, imgscore, nnidx, qstar);
    k_d2nn<<<64, 256, 0, stream>>>(cs, b2, nnidx, d2nn);
    k_topk<<<16, 256, 0, stream>>>(d2nn, cs, xhi, xlo, qstar, imgscore, out + B_IMG * IMG * IMG);
    k_bilinear<<<3136, 256, 0, stream>>>(scores, map0);
    k_blur_v<<<3136, 256, 0, stream>>>(map0, map1);
    k_blur_h<<<3136, 256, 0, stream>>>(map1, out);
}

// Round 2
// 1500.497 us; speedup vs baseline: 1.9360x; 1.9360x over previous
//
#include <hip/hip_runtime.h>
#include <math.h>

typedef unsigned short u16;
typedef unsigned int u32;
typedef unsigned long long u64;
typedef __attribute__((ext_vector_type(8))) short short8;
typedef __attribute__((ext_vector_type(4))) float f32x4;

#define B_IMG 16
#define EMB 1536
#define NPATCH 784
#define Q_TOT (B_IMG * NPATCH)   // 12544
#define NCORE 16384
#define NBLK 128                 // column blocks in the GEMM grid
#define IMG 224
#define KS 33
#define HALF 16
#define REFINE_W 4.0f

// ---------- helpers ----------

__device__ __forceinline__ u16 f2bf(float f) {
    u32 u = __float_as_uint(f);
    u32 r = u + 0x7FFFu + ((u >> 16) & 1u);   // RNE
    return (u16)(r >> 16);
}
__device__ __forceinline__ float bf2f(u16 h) {
    return __uint_as_float(((u32)h) << 16);
}
// monotonic total-order mapping for f32
__device__ __forceinline__ u32 fkey(float f) {
    u32 u = __float_as_uint(f);
    return (u & 0x80000000u) ? ~u : (u | 0x80000000u);
}
__device__ __forceinline__ float fkey_inv(u32 k) {
    u32 u = (k & 0x80000000u) ? (k ^ 0x80000000u) : ~k;
    return __uint_as_float(u);
}

// async global->LDS, 16B per lane
__device__ __forceinline__ void async_copy16(const u16* gsrc, u16* ldst) {
    auto g = reinterpret_cast<const __attribute__((address_space(1))) u32*>(
        reinterpret_cast<uintptr_t>(gsrc));
    auto l = reinterpret_cast<__attribute__((address_space(3))) u32*>(
        reinterpret_cast<uintptr_t>(ldst));
    __builtin_amdgcn_global_load_lds(g, l, 16, 0, 0);
}

// ---------- 0: init scratch ----------
__global__ void k_init(float* a2) {
    int i = blockIdx.x * 256 + threadIdx.x;
    if (i < Q_TOT) a2[i] = 0.f;
}

// ---------- 1: coreset -> bf16 + row norms ----------
__global__ void k_split_cs(const float* __restrict__ cs, u16* __restrict__ cshi,
                           float* __restrict__ b2) {
    __shared__ float sm[4];
    const int n = blockIdx.x;
    const int t = threadIdx.x;
    const size_t base = (size_t)n * EMB;
    float s = 0.f;
#pragma unroll
    for (int i = 0; i < 6; ++i) {
        const int e = t + i * 256;
        float v = cs[base + e];
        cshi[base + e] = f2bf(v);
        s += v * v;
    }
#pragma unroll
    for (int off = 32; off > 0; off >>= 1) s += __shfl_down(s, off, 64);
    if ((t & 63) == 0) sm[t >> 6] = s;
    __syncthreads();
    if (t == 0) b2[n] = sm[0] + sm[1] + sm[2] + sm[3];
}

// ---------- 2: avgpool(3,1,1) both layers + 2x nearest upsample of layer3,
//              transpose to [q][e], write bf16 + fp32, accumulate a2 ----------
__global__ void k_build_x(const float* __restrict__ f2, const float* __restrict__ f3,
                          u16* __restrict__ xhi, float* __restrict__ xf,
                          float* __restrict__ a2) {
    __shared__ float tile[32][33];
    __shared__ float red[8][33];
    const int tx = threadIdx.x, ty = threadIdx.y;
    const int hw0 = blockIdx.x * 32;
    const int e0 = blockIdx.y * 32;
    const int b = blockIdx.z;
    const int hw = hw0 + tx;
    const bool ok = hw < NPATCH;
    const int h = hw / 28, w = hw - h * 28;
    float sq = 0.f;
#pragma unroll
    for (int j = 0; j < 4; ++j) {
        const int el = ty + 8 * j;
        const int e = e0 + el;
        float v = 0.f;
        if (ok) {
            if (e < 512) {
                const float* p = f2 + (size_t)(b * 512 + e) * 784;
#pragma unroll
                for (int dy = -1; dy <= 1; ++dy) {
                    int yy = h + dy;
                    if (yy < 0 || yy >= 28) continue;
#pragma unroll
                    for (int dx = -1; dx <= 1; ++dx) {
                        int xx = w + dx;
                        if (xx < 0 || xx >= 28) continue;
                        v += p[yy * 28 + xx];
                    }
                }
            } else {
                const int c = e - 512;
                const int y3 = h >> 1, x3 = w >> 1;
                const float* p = f3 + (size_t)(b * 1024 + c) * 196;
#pragma unroll
                for (int dy = -1; dy <= 1; ++dy) {
                    int yy = y3 + dy;
                    if (yy < 0 || yy >= 14) continue;
#pragma unroll
                    for (int dx = -1; dx <= 1; ++dx) {
                        int xx = x3 + dx;
                        if (xx < 0 || xx >= 14) continue;
                        v += p[yy * 14 + xx];
                    }
                }
            }
            v *= (1.0f / 9.0f);
        }
        tile[el][tx] = v;
        sq += v * v;
    }
    red[ty][tx] = sq;
    __syncthreads();
#pragma unroll
    for (int j = 0; j < 4; ++j) {
        const int hwl = ty + 8 * j;
        const int hw2 = hw0 + hwl;
        if (hw2 < NPATCH) {
            const int q = b * NPATCH + hw2;
            const float v = tile[tx][hwl];
            xhi[(size_t)q * EMB + e0 + tx] = f2bf(v);
            xf[(size_t)q * EMB + e0 + tx] = v;
        }
    }
    if (ty == 0 && ok) {
        float s = 0.f;
#pragma unroll
        for (int y = 0; y < 8; ++y) s += red[y][tx];
        atomicAdd(&a2[b * NPATCH + hw], s);
    }
}

// ---------- 3: single-bf16 distance GEMM, per-(row,128-col-block) top-1 ----------
// 128x128 tile, BK=32, 4 waves 2x2, each wave 64x64 via 4x4 16x16x32 MFMAs.
// LDS k-chunk XOR-swizzled (chunk ^= (row>>1)&3) to kill phase bank conflicts;
// the swizzle is applied to the STAGING SOURCE so global_load_lds's
// lane-contiguous LDS destination is preserved.
__global__ __launch_bounds__(256) void k_gemm(
    const u16* __restrict__ xhi, const u16* __restrict__ cshi,
    const float* __restrict__ a2, const float* __restrict__ b2,
    u64* __restrict__ cand) {
    __shared__ short sA[128 * 32];
    __shared__ short sB[128 * 32];
    __shared__ u64 wred[128][2];
    const int tid = threadIdx.x;
    const int lane = tid & 63;
    const int wid = tid >> 6;
    const int wy = wid >> 1;
    const int wx = wid & 1;
    const int qd = lane >> 4;
    const int lr = lane & 15;

    const int m0 = blockIdx.y * 128;
    const int n0 = blockIdx.x * 128;

    // staging: chunk ch in [0,512): row=ch>>2, col-chunk swizzled
    const int ch0 = tid, ch1 = tid + 256;
    const int rA0 = ch0 >> 2, rA1 = ch1 >> 2;
    const int c0 = (((ch0 & 3) ^ ((rA0 >> 1) & 3))) * 8;
    const int c1 = (((ch1 & 3) ^ ((rA1 >> 1) & 3))) * 8;
    const size_t gA0 = (size_t)(m0 + rA0) * EMB + c0;
    const size_t gA1 = (size_t)(m0 + rA1) * EMB + c1;
    const size_t gB0 = (size_t)(n0 + rA0) * EMB + c0;
    const size_t gB1 = (size_t)(n0 + rA1) * EMB + c1;

    f32x4 acc[4][4];
#pragma unroll
    for (int i = 0; i < 4; ++i)
#pragma unroll
        for (int j = 0; j < 4; ++j) acc[i][j] = (f32x4){0.f, 0.f, 0.f, 0.f};

    // LDS read offsets (shorts), swizzle-matched
    int aidx[4], bidx[4];
#pragma unroll
    for (int mi = 0; mi < 4; ++mi) {
        const int wr = wy * 64 + mi * 16 + lr;
        aidx[mi] = (wr * 4 + (qd ^ ((wr >> 1) & 3))) * 8;
        const int nr = wx * 64 + mi * 16 + lr;
        bidx[mi] = (nr * 4 + (qd ^ ((nr >> 1) & 3))) * 8;
    }

    for (int ks = 0; ks < 48; ++ks) {
        const int kk = ks * 32;
        __syncthreads();
        async_copy16(xhi + gA0 + kk, (u16*)&sA[ch0 * 8]);
        async_copy16(xhi + gA1 + kk, (u16*)&sA[ch1 * 8]);
        async_copy16(cshi + gB0 + kk, (u16*)&sB[ch0 * 8]);
        async_copy16(cshi + gB1 + kk, (u16*)&sB[ch1 * 8]);
        __syncthreads();

        short8 ah[4];
#pragma unroll
        for (int mi = 0; mi < 4; ++mi) ah[mi] = *(const short8*)&sA[aidx[mi]];
#pragma unroll
        for (int nj = 0; nj < 4; ++nj) {
            short8 bh = *(const short8*)&sB[bidx[nj]];
#pragma unroll
            for (int mi = 0; mi < 4; ++mi)
                acc[mi][nj] = __builtin_amdgcn_mfma_f32_16x16x32_bf16(ah[mi], bh, acc[mi][nj], 0, 0, 0);
        }
    }

    // epilogue: d2 = a2[m] + b2[n] - 2*dot ; per-row min across this block
    // C/D layout: col = lane&15 (n), row = quad*4 + reg (m)
#pragma unroll
    for (int mi = 0; mi < 4; ++mi) {
#pragma unroll
        for (int r = 0; r < 4; ++r) {
            const int m_l = wy * 64 + mi * 16 + qd * 4 + r;
            const float a2v = a2[m0 + m_l];
            u64 best = ~0ull;
#pragma unroll
            for (int nj = 0; nj < 4; ++nj) {
                const int n_l = wx * 64 + nj * 16 + lr;
                float d2 = a2v + b2[n0 + n_l] - 2.0f * acc[mi][nj][r];
                u64 key = ((u64)fkey(d2) << 32) | (u32)(n0 + n_l);
                best = best < key ? best : key;
            }
#pragma unroll
            for (int s = 1; s < 16; s <<= 1) {
                u64 o = __shfl_xor(best, s, 64);
                best = best < o ? best : o;
            }
            if (lr == 0) wred[m_l][wx] = best;
        }
    }
    __syncthreads();
    if (tid < 128) {
        u64 a = wred[tid][0], b = wred[tid][1];
        cand[(size_t)(m0 + tid) * NBLK + blockIdx.x] = a < b ? a : b;
    }
}

// ---------- 4: exact fp32 refine of near-min candidates ----------
__global__ void k_refine(const u64* __restrict__ cand, const float* __restrict__ xf,
                         const float* __restrict__ cs,
                         float* __restrict__ scores, int* __restrict__ locs) {
    __shared__ u64 keys[NBLK];
    __shared__ float sx[EMB];
    __shared__ int clist[NBLK];
    __shared__ int ccount;
    __shared__ float fred[4];
    __shared__ float sd2min;
    const int row = blockIdx.x;
    const int t = threadIdx.x;
    if (t < NBLK) keys[t] = cand[(size_t)row * NBLK + t];
    for (int e = t; e < EMB; e += 256) sx[e] = xf[(size_t)row * EMB + e];
    if (t == 0) ccount = 0;
    __syncthreads();
    if (t < 64) {
        u64 m = keys[t] < keys[t + 64] ? keys[t] : keys[t + 64];
#pragma unroll
        for (int s = 32; s > 0; s >>= 1) {
            u64 o = __shfl_xor(m, s, 64);
            m = m < o ? m : o;
        }
        if (t == 0) sd2min = fkey_inv((u32)(m >> 32));
    }
    __syncthreads();
    const float lim = sd2min + REFINE_W;
    if (t < NBLK) {
        float d2a = fkey_inv((u32)(keys[t] >> 32));
        if (d2a <= lim) {
            int pos = atomicAdd(&ccount, 1);
            clist[pos] = (int)(keys[t] & 0xffffffffu);
        }
    }
    __syncthreads();
    const int nc = ccount;
    u64 best = ~0ull;   // valid in t==0 only
    for (int i = 0; i < nc; ++i) {
        const int n = clist[i];
        const float* c = cs + (size_t)n * EMB;
        float p = 0.f;
        for (int e = t; e < EMB; e += 256) {
            float d = sx[e] - c[e];
            p += d * d;
        }
#pragma unroll
        for (int s = 32; s > 0; s >>= 1) p += __shfl_down(p, s, 64);
        if ((t & 63) == 0) fred[t >> 6] = p;
        __syncthreads();
        if (t == 0) {
            float d2 = fred[0] + fred[1] + fred[2] + fred[3];
            u64 key = ((u64)fkey(d2) << 32) | (u32)n;
            best = best < key ? best : key;
        }
        __syncthreads();
    }
    if (t == 0) {
        float d2 = fkey_inv((u32)(best >> 32));
        scores[row] = sqrtf(fmaxf(d2, 1e-12f));
        locs[row] = (int)(best & 0xffffffffu);
    }
}

// ---------- 5: per-image argmax patch ----------
__global__ void k_argmax(const float* __restrict__ scores, const int* __restrict__ locs,
                         float* __restrict__ imgscore, int* __restrict__ nnidx,
                         int* __restrict__ qstar) {
    __shared__ u64 red[256];
    const int b = blockIdx.x, t = threadIdx.x;
    u64 best = 0;
    for (int p = t; p < NPATCH; p += 256) {
        u32 u = __float_as_uint(scores[b * NPATCH + p]);   // scores > 0
        u64 key = ((u64)u << 32) | (u32)(0xFFFFFFFFu - (u32)p);  // tie -> smallest p
        best = best > key ? best : key;
    }
    red[t] = best;
    __syncthreads();
    for (int s = 128; s > 0; s >>= 1) {
        if (t < s) { u64 o = red[t + s]; if (o > red[t]) red[t] = o; }
        __syncthreads();
    }
    if (t == 0) {
        u64 k = red[0];
        int p = (int)(0xFFFFFFFFu - (u32)(k & 0xFFFFFFFFu));
        imgscore[b] = __uint_as_float((u32)(k >> 32));
        nnidx[b] = locs[b * NPATCH + p];
        qstar[b] = b * NPATCH + p;
    }
}

// ---------- 6: d2 from each image's nn_sample to the whole coreset (fp32) ----------
__global__ void k_d2nn(const float* __restrict__ cs, const float* __restrict__ b2,
                       const int* __restrict__ nnidx, float* __restrict__ d2nn) {
    __shared__ float snn[16 * 512];
    const int t = threadIdx.x;
    const int n = blockIdx.x * 256 + t;
    float acc[16];
#pragma unroll
    for (int b = 0; b < 16; ++b) acc[b] = 0.f;
    for (int kc = 0; kc < EMB; kc += 512) {
        __syncthreads();
#pragma unroll
        for (int j = 0; j < 8; ++j) {
            int fid = t + j * 256;
            int row = fid >> 7;
            int c4 = fid & 127;
            ((float4*)snn)[row * 128 + c4] =
                ((const float4*)(cs + (size_t)nnidx[row] * EMB + kc))[c4];
        }
        __syncthreads();
        const float4* csrow = (const float4*)(cs + (size_t)n * EMB + kc);
        for (int k4 = 0; k4 < 128; ++k4) {
            float4 c4 = csrow[k4];
#pragma unroll
            for (int b = 0; b < 16; ++b) {
                float4 nb = ((const float4*)snn)[b * 128 + k4];
                acc[b] += c4.x * nb.x + c4.y * nb.y + c4.z * nb.z + c4.w * nb.w;
            }
        }
    }
#pragma unroll
    for (int b = 0; b < 16; ++b)
        d2nn[b * NCORE + n] = b2[nnidx[b]] + b2[n] - 2.f * acc[b];
}

// ---------- 7: top-9 supports, d_sup, softmax weight, anomaly score ----------
__global__ void k_topk(const float* __restrict__ d2nn, const float* __restrict__ cs,
                       const float* __restrict__ xf,
                       const int* __restrict__ qstar, const float* __restrict__ imgscore,
                       float* __restrict__ out_scores) {
    __shared__ int sel_idx[9];
    __shared__ float dsup[9];
    __shared__ u64 red[256];
    __shared__ float fred[256];
    const int b = blockIdx.x, t = threadIdx.x;

    for (int j = 0; j < 9; ++j) {
        u64 best = ~0ull;
        for (int n = t; n < NCORE; n += 256) {
            bool skip = false;
            for (int jj = 0; jj < j; ++jj) skip |= (sel_idx[jj] == n);
            if (skip) continue;
            u64 key = ((u64)fkey(d2nn[b * NCORE + n]) << 32) | (u32)n;
            best = best < key ? best : key;
        }
        red[t] = best;
        __syncthreads();
        for (int s = 128; s > 0; s >>= 1) {
            if (t < s) { u64 o = red[t + s]; if (o < red[t]) red[t] = o; }
            __syncthreads();
        }
        if (t == 0) sel_idx[j] = (int)(red[0] & 0xffffffffu);
        __syncthreads();
    }

    const int q = qstar[b];
    for (int j = 0; j < 9; ++j) {
        const int s = sel_idx[j];
        float p = 0.f;
        for (int e = t; e < EMB; e += 256) {
            float d = xf[(size_t)q * EMB + e] - cs[(size_t)s * EMB + e];
            p += d * d;
        }
        fred[t] = p;
        __syncthreads();
        for (int ss = 128; ss > 0; ss >>= 1) {
            if (t < ss) fred[t] += fred[t + ss];
            __syncthreads();
        }
        if (t == 0) dsup[j] = sqrtf(fmaxf(fred[0], 1e-12f));
        __syncthreads();
    }

    if (t == 0) {
        float m = dsup[0];
        for (int j = 1; j < 9; ++j) m = fmaxf(m, dsup[j]);
        float se = 0.f, e0 = 0.f;
        for (int j = 0; j < 9; ++j) {
            float e = expf(dsup[j] - m);
            se += e;
            if (j == 0) e0 = e;
        }
        out_scores[b] = (1.0f - e0 / se) * imgscore[b];
    }
}

// ---------- 8: bilinear 28->224 (half-pixel + edge clamp) ----------
__global__ void k_bilinear(const float* __restrict__ scores, float* __restrict__ map0) {
    int i = blockIdx.x * 256 + threadIdx.x;
    if (i >= B_IMG * IMG * IMG) return;
    int b = i / (IMG * IMG);
    int rem = i - b * (IMG * IMG);
    int y = rem / IMG, x = rem - y * IMG;
    float cy = (y + 0.5f) * 0.125f - 0.5f;
    float cx = (x + 0.5f) * 0.125f - 0.5f;
    float fy = cy - floorf(cy), fx = cx - floorf(cx);
    int y0 = (int)floorf(cy), x0 = (int)floorf(cx);
    int y1 = min(max(y0 + 1, 0), 27), x1 = min(max(x0 + 1, 0), 27);
    y0 = min(max(y0, 0), 27);
    x0 = min(max(x0, 0), 27);
    const float* s = scores + b * NPATCH;
    map0[i] = (1.f - fy) * ((1.f - fx) * s[y0 * 28 + x0] + fx * s[y0 * 28 + x1]) +
              fy * ((1.f - fx) * s[y1 * 28 + x0] + fx * s[y1 * 28 + x1]);
}

// ---------- 9/10: separable 33-tap Gaussian, sigma=4, reflect ----------
__global__ void k_blur_v(const float* __restrict__ src, float* __restrict__ dst) {
    __shared__ float wk[KS];
    int t = threadIdx.x;
    if (t < KS) { float d = (float)(t - HALF); wk[t] = expf(-(d * d) / 32.0f); }
    __syncthreads();
    float wsum = 0.f;
#pragma unroll
    for (int j = 0; j < KS; ++j) wsum += wk[j];
    int i = blockIdx.x * 256 + t;
    if (i >= B_IMG * IMG * IMG) return;
    int b = i / (IMG * IMG);
    int rem = i - b * (IMG * IMG);
    int y = rem / IMG, x = rem - y * IMG;
    float acc = 0.f;
#pragma unroll
    for (int j = 0; j < KS; ++j) {
        int yy = y - HALF + j;
        yy = yy < 0 ? -yy : (yy > 223 ? 446 - yy : yy);
        acc += wk[j] * src[b * (IMG * IMG) + yy * IMG + x];
    }
    dst[i] = acc / wsum;
}

__global__ void k_blur_h(const float* __restrict__ src, float* __restrict__ dst) {
    __shared__ float wk[KS];
    int t = threadIdx.x;
    if (t < KS) { float d = (float)(t - HALF); wk[t] = expf(-(d * d) / 32.0f); }
    __syncthreads();
    float wsum = 0.f;
#pragma unroll
    for (int j = 0; j < KS; ++j) wsum += wk[j];
    int i = blockIdx.x * 256 + t;
    if (i >= B_IMG * IMG * IMG) return;
    int b = i / (IMG * IMG);
    int rem = i - b * (IMG * IMG);
    int y = rem / IMG, x = rem - y * IMG;
    float acc = 0.f;
#pragma unroll
    for (int j = 0; j < KS; ++j) {
        int xx = x - HALF + j;
        xx = xx < 0 ? -xx : (xx > 223 ? 446 - xx : xx);
        acc += wk[j] * src[b * (IMG * IMG) + y * IMG + xx];
    }
    dst[i] = acc / wsum;
}

// ---------- launch ----------
extern "C" void kernel_launch(void* const* d_in, const int* in_sizes, int n_in,
                              void* d_out, int out_size, void* d_ws, size_t ws_size,
                              hipStream_t stream) {
    const float* f2 = (const float*)d_in[0];
    const float* f3 = (const float*)d_in[1];
    const float* cs = (const float*)d_in[2];
    float* out = (float*)d_out;

    char* w = (char*)d_ws;
    auto alloc = [&](size_t bytes) {
        char* p = w;
        w += (bytes + 255) & ~(size_t)255;
        return p;
    };
    u16* xhi = (u16*)alloc((size_t)Q_TOT * EMB * 2);
    float* xf = (float*)alloc((size_t)Q_TOT * EMB * 4);
    u16* cshi = (u16*)alloc((size_t)NCORE * EMB * 2);
    float* a2 = (float*)alloc(Q_TOT * 4);
    float* b2 = (float*)alloc(NCORE * 4);
    u64* cand = (u64*)alloc((size_t)Q_TOT * NBLK * 8);
    float* scores = (float*)alloc(Q_TOT * 4);
    int* locs = (int*)alloc(Q_TOT * 4);
    float* imgscore = (float*)alloc(B_IMG * 4);
    int* nnidx = (int*)alloc(B_IMG * 4);
    int* qstar = (int*)alloc(B_IMG * 4);
    float* d2nn = (float*)alloc((size_t)B_IMG * NCORE * 4);
    float* map0 = (float*)alloc((size_t)B_IMG * IMG * IMG * 4);
    float* map1 = (float*)alloc((size_t)B_IMG * IMG * IMG * 4);

    k_init<<<49, 256, 0, stream>>>(a2);
    k_split_cs<<<NCORE, 256, 0, stream>>>(cs, cshi, b2);
    k_build_x<<<dim3(25, 48, 16), dim3(32, 8), 0, stream>>>(f2, f3, xhi, xf, a2);
    k_gemm<<<dim3(NBLK, 98), 256, 0, stream>>>(xhi, cshi, a2, b2, cand);
    k_refine<<<Q_TOT, 256, 0, stream>>>(cand, xf, cs, scores, locs);
    k_argmax<<<16, 256, 0, stream>>>(scores, locs, imgscore, nnidx, qstar);
    k_d2nn<<<64, 256, 0, stream>>>(cs, b2, nnidx, d2nn);
    k_topk<<<16, 256, 0, stream>>>(d2nn, cs, xf, qstar, imgscore, out + B_IMG * IMG * IMG);
    k_bilinear<<<3136, 256, 0, stream>>>(scores, map0);
    k_blur_v<<<3136, 256, 0, stream>>>(map0, map1);
    k_blur_h<<<3136, 256, 0, stream>>>(map1, out);
}

// Round 4
// 1496.543 us; speedup vs baseline: 1.9412x; 1.0026x over previous
//
#include <hip/hip_runtime.h>
#include <math.h>

typedef unsigned char u8;
typedef unsigned short u16;
typedef unsigned int u32;
typedef unsigned long long u64;
typedef __attribute__((ext_vector_type(8))) int int8v;
typedef __attribute__((ext_vector_type(4))) int int4v;
typedef __attribute__((ext_vector_type(4))) float f32x4;

#define B_IMG 16
#define EMB 1536
#define NPATCH 784
#define Q_TOT (B_IMG * NPATCH)   // 12544
#define NCORE 16384
#define NBLK 128                 // 128-col blocks in the GEMM grid
#define BK 128                   // K per staging iter (fp8 bytes)
#define IMG 224
#define KS 33
#define HALF 16
#define REFINE_W 12.0f

// ---------- helpers ----------

// monotonic total-order mapping for f32
__device__ __forceinline__ u32 fkey(float f) {
    u32 u = __float_as_uint(f);
    return (u & 0x80000000u) ? ~u : (u | 0x80000000u);
}
__device__ __forceinline__ float fkey_inv(u32 k) {
    u32 u = (k & 0x80000000u) ? (k ^ 0x80000000u) : ~k;
    return __uint_as_float(u);
}

// f32 -> OCP e4m3fn, RNE (saturating)
__device__ __forceinline__ u32 f2e4m3(float f) {
    u32 x = __float_as_uint(f);
    u32 sign = (x >> 24) & 0x80u;
    x &= 0x7fffffffu;
    if (x >= 0x43E00000u) return sign | 0x7Eu;      // >= 448 -> 448
    u32 e = x >> 23;
    if (e >= 121) {                                  // normal e4m3 (>= 2^-6)
        u32 m = x & 0x7fffffu;
        u32 keep = m >> 20;
        u32 rest = m & 0xFFFFFu;
        u32 rnd = (rest > 0x80000u) || (rest == 0x80000u && (keep & 1u));
        u32 mant = keep + rnd;
        u32 e4 = e - 120;
        if (mant == 8) { mant = 0; e4 += 1; }
        return sign | (e4 << 3) | mant;
    }
    float a = __uint_as_float(x);
    u32 q = (u32)(a * 512.0f + 0.5f);                // denormal units of 2^-9
    if (q > 7) return sign | 0x08u;
    return sign | q;
}

// async global->LDS, 16B per lane
__device__ __forceinline__ void async_copy16(const void* gsrc, void* ldst) {
    auto g = reinterpret_cast<const __attribute__((address_space(1))) u32*>(
        reinterpret_cast<uintptr_t>(gsrc));
    auto l = reinterpret_cast<__attribute__((address_space(3))) u32*>(
        reinterpret_cast<uintptr_t>(ldst));
    __builtin_amdgcn_global_load_lds(g, l, 16, 0, 0);
}

// ---------- 1: coreset -> fp8 + row norms ----------
__global__ void k_split_cs(const float* __restrict__ cs, u8* __restrict__ cs8,
                           float* __restrict__ b2) {
    __shared__ float sm[4];
    const int n = blockIdx.x;
    const int t = threadIdx.x;
    const size_t base = (size_t)n * EMB;
    float s = 0.f;
#pragma unroll
    for (int i = 0; i < 6; ++i) {
        const int e = t + i * 256;
        float v = cs[base + e];
        cs8[base + e] = (u8)f2e4m3(v);
        s += v * v;
    }
#pragma unroll
    for (int off = 32; off > 0; off >>= 1) s += __shfl_down(s, off, 64);
    if ((t & 63) == 0) sm[t >> 6] = s;
    __syncthreads();
    if (t == 0) b2[n] = sm[0] + sm[1] + sm[2] + sm[3];
}

// ---------- 2: avgpool(3,1,1) + 2x nearest upsample of layer3,
//              transpose to [q][e], write fp8 + fp32 ----------
__global__ void k_build_x(const float* __restrict__ f2, const float* __restrict__ f3,
                          u8* __restrict__ x8, float* __restrict__ xf) {
    __shared__ float tile[32][33];
    const int tx = threadIdx.x, ty = threadIdx.y;
    const int hw0 = blockIdx.x * 32;
    const int e0 = blockIdx.y * 32;
    const int b = blockIdx.z;
    const int hw = hw0 + tx;
    const bool ok = hw < NPATCH;
    const int h = hw / 28, w = hw - h * 28;
#pragma unroll
    for (int j = 0; j < 4; ++j) {
        const int el = ty + 8 * j;
        const int e = e0 + el;
        float v = 0.f;
        if (ok) {
            if (e < 512) {
                const float* p = f2 + (size_t)(b * 512 + e) * 784;
#pragma unroll
                for (int dy = -1; dy <= 1; ++dy) {
                    int yy = h + dy;
                    if (yy < 0 || yy >= 28) continue;
#pragma unroll
                    for (int dx = -1; dx <= 1; ++dx) {
                        int xx = w + dx;
                        if (xx < 0 || xx >= 28) continue;
                        v += p[yy * 28 + xx];
                    }
                }
            } else {
                const int c = e - 512;
                const int y3 = h >> 1, x3 = w >> 1;
                const float* p = f3 + (size_t)(b * 1024 + c) * 196;
#pragma unroll
                for (int dy = -1; dy <= 1; ++dy) {
                    int yy = y3 + dy;
                    if (yy < 0 || yy >= 14) continue;
#pragma unroll
                    for (int dx = -1; dx <= 1; ++dx) {
                        int xx = x3 + dx;
                        if (xx < 0 || xx >= 14) continue;
                        v += p[yy * 14 + xx];
                    }
                }
            }
            v *= (1.0f / 9.0f);
        }
        tile[el][tx] = v;
    }
    __syncthreads();
#pragma unroll
    for (int j = 0; j < 4; ++j) {
        const int hwl = ty + 8 * j;
        const int hw2 = hw0 + hwl;
        if (hw2 < NPATCH) {
            const int q = b * NPATCH + hw2;
            const float v = tile[tx][hwl];
            x8[(size_t)q * EMB + e0 + tx] = (u8)f2e4m3(v);
            xf[(size_t)q * EMB + e0 + tx] = v;
        }
    }
}

// ---------- 3: MX-fp8 distance GEMM (scales=1.0), top-1 per 64-col half-block ----
// 128x128 tile, BK=128 (fp8), 4 waves 2x2, each wave 64x64 via 4x4 16x16x128 MFMAs.
// LDS 16B-chunk XOR-swizzled by (row&7); swizzle applied on the STAGING SOURCE so
// global_load_lds's lane-contiguous LDS destination is preserved.
// Rank key = b2[n] - 2*dot (a2[m] is row-constant, dropped).
__global__ __launch_bounds__(256) void k_gemm(
    const u8* __restrict__ x8, const u8* __restrict__ cs8,
    const float* __restrict__ b2, u64* __restrict__ cand) {
    __shared__ __align__(16) u8 sA[128 * BK];
    __shared__ __align__(16) u8 sB[128 * BK];
    __shared__ u64 wred[128][2];
    const int tid = threadIdx.x;
    const int lane = tid & 63;
    const int wid = tid >> 6;
    const int wy = wid >> 1;
    const int wx = wid & 1;
    const int qd = lane >> 4;
    const int lr = lane & 15;

    const int m0 = blockIdx.y * 128;
    const int n0 = blockIdx.x * 128;

    // staging: slot s = tid + j*256; r = s>>3, physical chunk p = s&7
    size_t srcA[4], srcB[4];
    int dst[4];
#pragma unroll
    for (int j = 0; j < 4; ++j) {
        const int s = tid + j * 256;
        const int r = s >> 3, p = s & 7;
        const int col = (p ^ (r & 7)) * 16;
        srcA[j] = (size_t)(m0 + r) * EMB + col;
        srcB[j] = (size_t)(n0 + r) * EMB + col;
        dst[j] = s * 16;
    }

    f32x4 acc[4][4];
#pragma unroll
    for (int i = 0; i < 4; ++i)
#pragma unroll
        for (int j = 0; j < 4; ++j) acc[i][j] = (f32x4){0.f, 0.f, 0.f, 0.f};

    // LDS read offsets (bytes), swizzle-matched: logical chunks qd*2, qd*2+1
    int aoff[4][2], boff[4][2];
    const int sw = lr & 7;
#pragma unroll
    for (int mi = 0; mi < 4; ++mi) {
        const int ra = wy * 64 + mi * 16 + lr;
        const int rb = wx * 64 + mi * 16 + lr;
        aoff[mi][0] = ra * BK + ((qd * 2) ^ sw) * 16;
        aoff[mi][1] = ra * BK + ((qd * 2 + 1) ^ sw) * 16;
        boff[mi][0] = rb * BK + ((qd * 2) ^ sw) * 16;
        boff[mi][1] = rb * BK + ((qd * 2 + 1) ^ sw) * 16;
    }

    for (int ks = 0; ks < EMB / BK; ++ks) {   // 12 iters
        const int kk = ks * BK;
        __syncthreads();
#pragma unroll
        for (int j = 0; j < 4; ++j) {
            async_copy16(x8 + srcA[j] + kk, sA + dst[j]);
            async_copy16(cs8 + srcB[j] + kk, sB + dst[j]);
        }
        __syncthreads();

        int8v a[4];
#pragma unroll
        for (int mi = 0; mi < 4; ++mi) {
            *(int4v*)&a[mi] = *(const int4v*)(sA + aoff[mi][0]);
            *(((int4v*)&a[mi]) + 1) = *(const int4v*)(sA + aoff[mi][1]);
        }
#pragma unroll
        for (int nj = 0; nj < 4; ++nj) {
            int8v bfr;
            *(int4v*)&bfr = *(const int4v*)(sB + boff[nj][0]);
            *(((int4v*)&bfr) + 1) = *(const int4v*)(sB + boff[nj][1]);
#pragma unroll
            for (int mi = 0; mi < 4; ++mi)
                acc[mi][nj] = __builtin_amdgcn_mfma_scale_f32_16x16x128_f8f6f4(
                    a[mi], bfr, acc[mi][nj], 0, 0, 0, 0x7F7F7F7F, 0, 0x7F7F7F7F);
        }
    }

    // epilogue: key value = b2[n] - 2*dot ; min per (row, 64-col half-block)
    // C/D layout: col = lane&15 (n), row = quad*4 + reg (m)
#pragma unroll
    for (int mi = 0; mi < 4; ++mi) {
#pragma unroll
        for (int r = 0; r < 4; ++r) {
            const int m_l = wy * 64 + mi * 16 + qd * 4 + r;
            u64 best = ~0ull;
#pragma unroll
            for (int nj = 0; nj < 4; ++nj) {
                const int n_l = wx * 64 + nj * 16 + lr;
                float v = b2[n0 + n_l] - 2.0f * acc[mi][nj][r];
                u64 key = ((u64)fkey(v) << 32) | (u32)(n0 + n_l);
                best = best < key ? best : key;
            }
#pragma unroll
            for (int s = 1; s < 16; s <<= 1) {
                u64 o = __shfl_xor(best, s, 64);
                best = best < o ? best : o;
            }
            if (lr == 0) wred[m_l][wx] = best;
        }
    }
    __syncthreads();
    {
        const int row = tid >> 1, half = tid & 1;
        cand[((size_t)(m0 + row) * NBLK + blockIdx.x) * 2 + half] = wred[row][half];
    }
}

// ---------- 4: exact fp32 refine of near-min candidates ----------
__global__ void k_refine(const u64* __restrict__ cand, const float* __restrict__ xf,
                         const float* __restrict__ cs,
                         float* __restrict__ scores, int* __restrict__ locs) {
    __shared__ u64 keys[2 * NBLK];
    __shared__ float sx[EMB];
    __shared__ float fred[256];
    __shared__ u64 ured[256];
    __shared__ int clist[16];
    __shared__ int ccount;
    __shared__ float s_a2, s_lim;
    const int row = blockIdx.x;
    const int t = threadIdx.x;
    keys[t] = cand[(size_t)row * 256 + t];
    float p = 0.f;
    for (int e = t; e < EMB; e += 256) {
        float v = xf[(size_t)row * EMB + e];
        sx[e] = v;
        p += v * v;
    }
    fred[t] = p;
    if (t == 0) ccount = 0;
    __syncthreads();
    for (int s = 128; s > 0; s >>= 1) {
        if (t < s) fred[t] += fred[t + s];
        __syncthreads();
    }
    if (t == 0) s_a2 = fred[0];
    ured[t] = keys[t];
    __syncthreads();
    for (int s = 128; s > 0; s >>= 1) {
        if (t < s) { u64 o = ured[t + s]; if (o < ured[t]) ured[t] = o; }
        __syncthreads();
    }
    if (t == 0) s_lim = s_a2 + fkey_inv((u32)(ured[0] >> 32)) + REFINE_W;
    __syncthreads();
    {
        float d2a = s_a2 + fkey_inv((u32)(keys[t] >> 32));
        if (d2a <= s_lim) {
            int pos = atomicAdd(&ccount, 1);
            if (pos < 16) clist[pos] = (int)(keys[t] & 0xffffffffu);
        }
    }
    __syncthreads();
    const int nc = min(ccount, 16);
    u64 best = ~0ull;   // valid in t==0 only
    for (int i = 0; i < nc; ++i) {
        const int n = clist[i];
        const float* c = cs + (size_t)n * EMB;
        float q = 0.f;
        for (int e = t; e < EMB; e += 256) {
            float d = sx[e] - c[e];
            q += d * d;
        }
        fred[t] = q;
        __syncthreads();
        for (int s = 128; s > 0; s >>= 1) {
            if (t < s) fred[t] += fred[t + s];
            __syncthreads();
        }
        if (t == 0) {
            u64 key = ((u64)fkey(fred[0]) << 32) | (u32)n;
            best = best < key ? best : key;
        }
        __syncthreads();
    }
    if (t == 0) {
        float d2 = fkey_inv((u32)(best >> 32));
        scores[row] = sqrtf(fmaxf(d2, 1e-12f));
        locs[row] = (int)(best & 0xffffffffu);
    }
}

// ---------- 5: per-image argmax patch ----------
__global__ void k_argmax(const float* __restrict__ scores, const int* __restrict__ locs,
                         float* __restrict__ imgscore, int* __restrict__ nnidx,
                         int* __restrict__ qstar) {
    __shared__ u64 red[256];
    const int b = blockIdx.x, t = threadIdx.x;
    u64 best = 0;
    for (int p = t; p < NPATCH; p += 256) {
        u32 u = __float_as_uint(scores[b * NPATCH + p]);   // scores > 0
        u64 key = ((u64)u << 32) | (u32)(0xFFFFFFFFu - (u32)p);  // tie -> smallest p
        best = best > key ? best : key;
    }
    red[t] = best;
    __syncthreads();
    for (int s = 128; s > 0; s >>= 1) {
        if (t < s) { u64 o = red[t + s]; if (o > red[t]) red[t] = o; }
        __syncthreads();
    }
    if (t == 0) {
        u64 k = red[0];
        int p = (int)(0xFFFFFFFFu - (u32)(k & 0xFFFFFFFFu));
        imgscore[b] = __uint_as_float((u32)(k >> 32));
        nnidx[b] = locs[b * NPATCH + p];
        qstar[b] = b * NPATCH + p;
    }
}

// ---------- 6: partial dots nn_sample . coreset, 4-way K-split ----------
__global__ void k_d2nn(const float* __restrict__ cs, const int* __restrict__ nnidx,
                       float* __restrict__ dpart) {
    __shared__ float snn[16 * 384];
    const int t = threadIdx.x;
    const int nb = blockIdx.x & 63, ksl = blockIdx.x >> 6;
    const int n = nb * 256 + t;
    const int k0 = ksl * 384;
#pragma unroll
    for (int j = 0; j < 6; ++j) {
        int fid = t + j * 256;           // 0..1535 float4 slots
        int row = fid / 96;
        int c4 = fid - row * 96;
        ((float4*)snn)[row * 96 + c4] =
            ((const float4*)(cs + (size_t)nnidx[row] * EMB + k0))[c4];
    }
    __syncthreads();
    float acc[16];
#pragma unroll
    for (int b = 0; b < 16; ++b) acc[b] = 0.f;
    const float4* csrow = (const float4*)(cs + (size_t)n * EMB + k0);
    for (int k4 = 0; k4 < 96; ++k4) {
        float4 c4 = csrow[k4];
#pragma unroll
        for (int b = 0; b < 16; ++b) {
            float4 nb4 = ((const float4*)snn)[b * 96 + k4];
            acc[b] += c4.x * nb4.x + c4.y * nb4.y + c4.z * nb4.z + c4.w * nb4.w;
        }
    }
#pragma unroll
    for (int b = 0; b < 16; ++b)
        dpart[((size_t)ksl * 16 + b) * NCORE + n] = acc[b];
}

// ---------- 7: top-9 supports, d_sup, softmax weight, anomaly score ----------
__global__ void k_topk(const float* __restrict__ dpart, const float* __restrict__ b2,
                       const int* __restrict__ nnidx,
                       const float* __restrict__ cs, const float* __restrict__ xf,
                       const int* __restrict__ qstar, const float* __restrict__ imgscore,
                       float* __restrict__ out_scores) {
    __shared__ float sd2[NCORE];     // 64 KB
    __shared__ int sel_idx[9];
    __shared__ float dsup[9];
    __shared__ u64 red[256];
    __shared__ float fred[256];
    const int b = blockIdx.x, t = threadIdx.x;
    const float bnn = b2[nnidx[b]];
    for (int n = t; n < NCORE; n += 256) {
        float dot = dpart[(0 * 16 + b) * NCORE + n] + dpart[(1 * 16 + b) * NCORE + n] +
                    dpart[(2 * 16 + b) * NCORE + n] + dpart[(3 * 16 + b) * NCORE + n];
        sd2[n] = bnn + b2[n] - 2.f * dot;
    }
    __syncthreads();

    for (int j = 0; j < 9; ++j) {
        u64 best = ~0ull;
        for (int n = t; n < NCORE; n += 256) {
            u64 key = ((u64)fkey(sd2[n]) << 32) | (u32)n;
            best = best < key ? best : key;
        }
        red[t] = best;
        __syncthreads();
        for (int s = 128; s > 0; s >>= 1) {
            if (t < s) { u64 o = red[t + s]; if (o < red[t]) red[t] = o; }
            __syncthreads();
        }
        if (t == 0) {
            int sel = (int)(red[0] & 0xffffffffu);
            sel_idx[j] = sel;
            sd2[sel] = __uint_as_float(0x7F800000u);   // +inf: exclude from later rounds
        }
        __syncthreads();
    }

    const int q = qstar[b];
    for (int j = 0; j < 9; ++j) {
        const int s = sel_idx[j];
        float p = 0.f;
        for (int e = t; e < EMB; e += 256) {
            float d = xf[(size_t)q * EMB + e] - cs[(size_t)s * EMB + e];
            p += d * d;
        }
        fred[t] = p;
        __syncthreads();
        for (int ss = 128; ss > 0; ss >>= 1) {
            if (t < ss) fred[t] += fred[t + ss];
            __syncthreads();
        }
        if (t == 0) dsup[j] = sqrtf(fmaxf(fred[0], 1e-12f));
        __syncthreads();
    }

    if (t == 0) {
        float m = dsup[0];
        for (int j = 1; j < 9; ++j) m = fmaxf(m, dsup[j]);
        float se = 0.f, e0 = 0.f;
        for (int j = 0; j < 9; ++j) {
            float e = expf(dsup[j] - m);
            se += e;
            if (j == 0) e0 = e;
        }
        out_scores[b] = (1.0f - e0 / se) * imgscore[b];
    }
}

// ---------- 8: bilinear in x only: scores[b][28][28] -> Sx[b][28][224] ----------
__global__ void k_bilx(const float* __restrict__ scores, float* __restrict__ Sx) {
    int i = blockIdx.x * 256 + threadIdx.x;
    if (i >= B_IMG * 28 * IMG) return;
    int x = i % IMG;
    int br = i / IMG;
    int r = br % 28, b = br / 28;
    float cx = (x + 0.5f) * 0.125f - 0.5f;
    int x0 = (int)floorf(cx);
    float fx = cx - (float)x0;
    int x1 = min(max(x0 + 1, 0), 27);
    x0 = min(max(x0, 0), 27);
    const float* s = scores + b * NPATCH + r * 28;
    Sx[i] = (1.f - fx) * s[x0] + fx * s[x1];
}

// ---------- 9: fused (bilinear-y + vertical Gaussian): 28-tap row combine ----------
__global__ void k_blur_vf(const float* __restrict__ Sx, float* __restrict__ out1) {
    __shared__ float wv[28];
    const int y = blockIdx.x, b = blockIdx.y, t = threadIdx.x;
    if (t < 28) wv[t] = 0.f;
    __syncthreads();
    if (t == 0) {
        float wsum = 0.f;
        for (int j = 0; j < KS; ++j) {
            float d = (float)(j - HALF);
            wsum += expf(-(d * d) / 32.0f);
        }
        for (int j = 0; j < KS; ++j) {
            int yy = y - HALF + j;
            yy = yy < 0 ? -yy : (yy > 223 ? 446 - yy : yy);
            float cy = (yy + 0.5f) * 0.125f - 0.5f;
            int y0 = (int)floorf(cy);
            float fy = cy - (float)y0;
            int y1 = min(max(y0 + 1, 0), 27);
            y0 = min(max(y0, 0), 27);
            float d = (float)(j - HALF);
            float wkj = expf(-(d * d) / 32.0f) / wsum;
            wv[y0] += (1.f - fy) * wkj;
            wv[y1] += fy * wkj;
        }
    }
    __syncthreads();
    if (t < IMG) {
        float acc = 0.f;
#pragma unroll
        for (int r = 0; r < 28; ++r) acc += wv[r] * Sx[(b * 28 + r) * IMG + t];
        out1[((size_t)b * IMG + y) * IMG + t] = acc;
    }
}

// ---------- 10: horizontal Gaussian (33-tap, reflect), LDS row ----------
__global__ void k_blur_h(const float* __restrict__ out1, float* __restrict__ out) {
    __shared__ float row[IMG];
    __shared__ float wk[KS];
    const int y = blockIdx.x, b = blockIdx.y, t = threadIdx.x;
    if (t < IMG) row[t] = out1[((size_t)b * IMG + y) * IMG + t];
    if (t < KS) {                 // FIX: was threads [IMG, IMG+KS) -> only 32 of 33 taps
        float d = (float)(t - HALF);
        wk[t] = expf(-(d * d) / 32.0f);
    }
    __syncthreads();
    if (t < IMG) {
        float wsum = 0.f, acc = 0.f;
#pragma unroll
        for (int j = 0; j < KS; ++j) wsum += wk[j];
#pragma unroll
        for (int j = 0; j < KS; ++j) {
            int xx = t - HALF + j;
            xx = xx < 0 ? -xx : (xx > 223 ? 446 - xx : xx);
            acc += wk[j] * row[xx];
        }
        out[((size_t)b * IMG + y) * IMG + t] = acc / wsum;
    }
}

// ---------- launch ----------
extern "C" void kernel_launch(void* const* d_in, const int* in_sizes, int n_in,
                              void* d_out, int out_size, void* d_ws, size_t ws_size,
                              hipStream_t stream) {
    const float* f2 = (const float*)d_in[0];
    const float* f3 = (const float*)d_in[1];
    const float* cs = (const float*)d_in[2];
    float* out = (float*)d_out;

    char* w = (char*)d_ws;
    auto alloc = [&](size_t bytes) {
        char* p = w;
        w += (bytes + 255) & ~(size_t)255;
        return p;
    };
    u8* x8 = (u8*)alloc((size_t)Q_TOT * EMB);
    float* xf = (float*)alloc((size_t)Q_TOT * EMB * 4);
    u8* cs8 = (u8*)alloc((size_t)NCORE * EMB);
    float* b2 = (float*)alloc(NCORE * 4);
    u64* cand = (u64*)alloc((size_t)Q_TOT * NBLK * 2 * 8);
    float* scores = (float*)alloc(Q_TOT * 4);
    int* locs = (int*)alloc(Q_TOT * 4);
    float* imgscore = (float*)alloc(B_IMG * 4);
    int* nnidx = (int*)alloc(B_IMG * 4);
    int* qstar = (int*)alloc(B_IMG * 4);
    float* dpart = (float*)alloc((size_t)4 * B_IMG * NCORE * 4);
    float* Sx = (float*)alloc((size_t)B_IMG * 28 * IMG * 4);
    float* map1 = (float*)alloc((size_t)B_IMG * IMG * IMG * 4);

    k_split_cs<<<NCORE, 256, 0, stream>>>(cs, cs8, b2);
    k_build_x<<<dim3(25, 48, 16), dim3(32, 8), 0, stream>>>(f2, f3, x8, xf);
    k_gemm<<<dim3(NBLK, 98), 256, 0, stream>>>(x8, cs8, b2, cand);
    k_refine<<<Q_TOT, 256, 0, stream>>>(cand, xf, cs, scores, locs);
    k_argmax<<<16, 256, 0, stream>>>(scores, locs, imgscore, nnidx, qstar);
    k_d2nn<<<256, 256, 0, stream>>>(cs, nnidx, dpart);
    k_topk<<<16, 256, 0, stream>>>(dpart, b2, nnidx, cs, xf, qstar, imgscore,
                                   out + B_IMG * IMG * IMG);
    k_bilx<<<(B_IMG * 28 * IMG + 255) / 256, 256, 0, stream>>>(scores, Sx);
    k_blur_vf<<<dim3(IMG, B_IMG), 256, 0, stream>>>(Sx, map1);
    k_blur_h<<<dim3(IMG, B_IMG), 256, 0, stream>>>(map1, out);
}